// Round 4
// baseline (99.580 us; speedup 1.0000x reference)
//
#include <hip/hip_runtime.h>

#define B_   256
#define E_   64
#define G_   2000
#define P_   512
#define K2   2048      // G padded to multiple of BK (xb zero-filled)
#define BK   64
#define NS   (K2/BK)   // 32 K-steps
#define PT   64        // p columns per block: 2 wave-slabs of 32

typedef __bf16 bf16x8 __attribute__((ext_vector_type(8)));
typedef float floatx16 __attribute__((ext_vector_type(16)));
typedef unsigned int u32;

__global__ __launch_bounds__(256)
void cvt_x_kernel(const float* __restrict__ x, __bf16* __restrict__ xb) {
    int col = blockIdx.x * 256 + threadIdx.x;   // 0..2047
    int row = blockIdx.y;
    float v = (col < G_) ? x[(size_t)row * G_ + col] : 0.f;
    xb[(size_t)row * K2 + col] = (__bf16)v;
}

// async global->LDS, 16B per lane, linear LDS dest (uniform base + lane*16)
__device__ __forceinline__ void gll16(const void* g, void* l) {
    __builtin_amdgcn_global_load_lds(
        (const __attribute__((address_space(1))) u32*)(uintptr_t)g,
        (__attribute__((address_space(3))) u32*)(uintptr_t)l,
        16, 0, 0);
}

// A (=x) in LDS: [buf][row(256)][64k] bf16, 128B rows, 16B chunks XOR-swizzled
// by (row&7): LDS chunk c of row r holds x k-chunk (c ^ (r&7)). Linear gll16
// dest + pre-swizzled global source; swizzled ds_read (rule #21).
// B (=weight*mask) gathered straight to registers: for 32x32x16 MFMA the
// B-frag is n=lane&31 (=p), k=(lane>>5)*8+j -> 8 strided dwords per frag.
template<bool USE_WS>
__global__ __launch_bounds__(256, 2)
void masked_gemm_kernel(const float* __restrict__ x,
                        const __bf16* __restrict__ xb,
                        const float* __restrict__ weight,
                        const float* __restrict__ bias,
                        const float* __restrict__ mask,
                        float* __restrict__ out)
{
    __shared__ __attribute__((aligned(128))) __bf16 alds[2][B_ * BK];  // 2 x 32KB

    const int tid  = threadIdx.x;
    const int lane = tid & 63;
    const int wv   = tid >> 6;           // wave: bit0 = row-half, bit1 = p-slab
    const int ln   = lane & 31;          // p col in slab / A row in mi tile
    const int hi   = lane >> 5;          // k-octet half (0..1)

    const int bid = blockIdx.x;          // 512 blocks
    const int pt  = bid & 7;             // p-tile -> XCD (mask slab L2-hot)
    const int e   = bid >> 3;            // expert 0..63
    const int pw  = pt * PT + (wv >> 1) * 32;
    const int mrow0 = (wv & 1) * 128;

    const float* wcol = weight + (size_t)e * G_ * P_ + pw + ln;
    const float* mcol = mask   + (size_t)(pw + ln);

    // staging lane coords: 8 rows/instr, 16B chunk within 128B row
    const int srow = lane >> 3;          // 0..7
    const int schk = lane & 7;           // 0..7

    floatx16 acc[4];
    #pragma unroll
    for (int i = 0; i < 4; ++i) acc[i] = (floatx16)0.f;

    float wr[32], mr[32];
    bf16x8 bcur[4];

    // ---- prologue: stage A tile 0, gather+cvt B block 0 ----
    #pragma unroll
    for (int i = 0; i < 8; ++i) {
        const int r0  = wv * 64 + i * 8;
        const int row = r0 + srow;
        if (USE_WS) {
            gll16(xb + (size_t)row * K2 + ((schk ^ (row & 7)) << 3),
                  (void*)&alds[0][r0 * BK]);
        } else {
            const int k0 = (schk ^ (row & 7)) << 3;
            bf16x8 v;
            #pragma unroll
            for (int j = 0; j < 8; ++j)
                v[j] = (k0 + j < G_) ? (__bf16)x[(size_t)row * G_ + k0 + j] : (__bf16)0.f;
            *(bf16x8*)&alds[0][row * BK + schk * 8] = v;
        }
    }
    #pragma unroll
    for (int kk = 0; kk < 4; ++kk)
        #pragma unroll
        for (int j = 0; j < 8; ++j) {
            const int g = kk * 16 + hi * 8 + j;          // all < 2000
            wr[kk * 8 + j] = wcol[(size_t)g * P_];
            mr[kk * 8 + j] = mcol[(size_t)g * P_];
        }
    #pragma unroll
    for (int kk = 0; kk < 4; ++kk)
        #pragma unroll
        for (int j = 0; j < 8; ++j)
            bcur[kk][j] = (__bf16)(wr[kk * 8 + j] * mr[kk * 8 + j]);
    __syncthreads();

    // ---- main loop: compute(t) reads only LDS+regs; prefetch(t+1) in flight ----
    for (int s = 0; s < NS; ++s) {
        const int buf = s & 1;
        const bool more = (s + 1) < NS;
        const int kb1 = (s + 1) * BK;

        if (more) {
            // stage A tile t+1 (async, drains at barrier)
            #pragma unroll
            for (int i = 0; i < 8; ++i) {
                const int r0  = wv * 64 + i * 8;
                const int row = r0 + srow;
                if (USE_WS) {
                    gll16(xb + (size_t)row * K2 + kb1 + ((schk ^ (row & 7)) << 3),
                          (void*)&alds[buf ^ 1][r0 * BK]);
                } else {
                    const int k0 = kb1 + ((schk ^ (row & 7)) << 3);
                    bf16x8 v;
                    #pragma unroll
                    for (int j = 0; j < 8; ++j)
                        v[j] = (k0 + j < G_) ? (__bf16)x[(size_t)row * G_ + k0 + j] : (__bf16)0.f;
                    *(bf16x8*)&alds[buf ^ 1][row * BK + schk * 8] = v;
                }
            }
            // weight/mask gather t+1 (uniform-branch octet tail guard)
            if (kb1 + BK <= G_) {
                #pragma unroll
                for (int kk = 0; kk < 4; ++kk)
                    #pragma unroll
                    for (int j = 0; j < 8; ++j) {
                        const int g = kb1 + kk * 16 + hi * 8 + j;
                        wr[kk * 8 + j] = wcol[(size_t)g * P_];
                        mr[kk * 8 + j] = mcol[(size_t)g * P_];
                    }
            } else {
                #pragma unroll
                for (int kk = 0; kk < 4; ++kk)
                    #pragma unroll
                    for (int j = 0; j < 8; ++j) {
                        const int g = kb1 + kk * 16 + hi * 8 + j;
                        const bool ok = g < G_;            // 2000%8==0: octet-uniform
                        wr[kk * 8 + j] = ok ? wcol[(size_t)g * P_] : 0.f;
                        mr[kk * 8 + j] = ok ? mcol[(size_t)g * P_] : 0.f;
                    }
            }
        }

        // compute: 16 ds_read_b128 + 16 MFMA(32x32x16), no vmem dependence
        #pragma unroll
        for (int kk = 0; kk < 4; ++kk) {
            #pragma unroll
            for (int mi = 0; mi < 4; ++mi) {
                const int row = mrow0 + mi * 32 + ln;
                const int cc  = (kk * 2 + hi) ^ (row & 7);
                bf16x8 a = *(const bf16x8*)&alds[buf][row * BK + cc * 8];
                acc[mi] = __builtin_amdgcn_mfma_f32_32x32x16_bf16(a, bcur[kk], acc[mi], 0, 0, 0);
            }
        }

        // cvt next B block (waits the w/m loads); barrier drains gll (vmcnt 0)
        if (more) {
            #pragma unroll
            for (int kk = 0; kk < 4; ++kk)
                #pragma unroll
                for (int j = 0; j < 8; ++j)
                    bcur[kk][j] = (__bf16)(wr[kk * 8 + j] * mr[kk * 8 + j]);
        }
        __syncthreads();
    }

    // ---- epilogue: D col n=p=lane&31, row m=(r&3)+8*(r>>2)+4*(lane>>5) ----
    const float bv = bias[e * P_ + pw + ln];
    #pragma unroll
    for (int mi = 0; mi < 4; ++mi) {
        #pragma unroll
        for (int r = 0; r < 16; ++r) {
            const int b = mrow0 + mi * 32 + (r & 3) + 8 * (r >> 2) + 4 * hi;
            __builtin_nontemporal_store(acc[mi][r] + bv,
                &out[(size_t)b * (E_ * P_) + (size_t)e * P_ + pw + ln]);
        }
    }
}

extern "C" void kernel_launch(void* const* d_in, const int* in_sizes, int n_in,
                              void* d_out, int out_size, void* d_ws, size_t ws_size,
                              hipStream_t stream) {
    const float* x      = (const float*)d_in[0];
    const float* weight = (const float*)d_in[1];
    const float* bias   = (const float*)d_in[2];
    const float* mask   = (const float*)d_in[3];
    float* out = (float*)d_out;

    const size_t xb_bytes = (size_t)B_ * K2 * sizeof(__bf16);
    if (ws_size >= xb_bytes) {
        __bf16* xb = (__bf16*)d_ws;
        dim3 g1(K2 / 256, B_);
        cvt_x_kernel<<<g1, dim3(256), 0, stream>>>(x, xb);
        masked_gemm_kernel<true><<<dim3(512), dim3(256), 0, stream>>>(x, xb, weight, bias, mask, out);
    } else {
        masked_gemm_kernel<false><<<dim3(512), dim3(256), 0, stream>>>(x, nullptr, weight, bias, mask, out);
    }
}

// Round 5
// 89.764 us; speedup vs baseline: 1.1094x; 1.1094x over previous
//
#include <hip/hip_runtime.h>

#define B_   256
#define E_   64
#define G_   2000
#define P_   512
#define K2   2048      // G padded to multiple of BK (xb zero-filled)
#define BK   32
#define NS   (K2/BK)   // 64 K-steps
#define PT   64        // p columns per block: 2 wave-slabs of 32

typedef __bf16 bf16x8 __attribute__((ext_vector_type(8)));
typedef float floatx16 __attribute__((ext_vector_type(16)));
typedef unsigned int u32;

__global__ __launch_bounds__(256)
void cvt_x_kernel(const float* __restrict__ x, __bf16* __restrict__ xb) {
    int col = blockIdx.x * 256 + threadIdx.x;   // 0..2047
    int row = blockIdx.y;
    float v = (col < G_) ? x[(size_t)row * G_ + col] : 0.f;
    xb[(size_t)row * K2 + col] = (__bf16)v;
}

// async global->LDS, 16B per lane, linear LDS dest (uniform base + lane*16)
__device__ __forceinline__ void gll16(const void* g, void* l) {
    __builtin_amdgcn_global_load_lds(
        (const __attribute__((address_space(1))) u32*)(uintptr_t)g,
        (__attribute__((address_space(3))) u32*)(uintptr_t)l,
        16, 0, 0);
}

// All staging via global_load_lds, issued a FULL step before use:
//  A (=x bf16): [buf][row(256)][32k], 64B rows; 16B chunk c of row r holds
//    global chunk c ^ ((r>>1)&3)  -> ds_read_b128 spreads 8 rows over all
//    32 banks (4 dwords/bank, optimal). Linear gll dest + pre-swizzled src.
//  W,M (f32):   [buf][g(32)][p(64)], linear (p-contiguous source rows).
// B-frags built per step from W/M LDS: b32 gather at bank=p (lanes 0..31
// distinct banks; lanes 32..63 2-way = free), f32 mul, cvt to bf16.
template<bool USE_WS>
__global__ __launch_bounds__(256, 2)
void masked_gemm_kernel(const float* __restrict__ x,
                        const __bf16* __restrict__ xb,
                        const float* __restrict__ weight,
                        const float* __restrict__ bias,
                        const float* __restrict__ mask,
                        float* __restrict__ out)
{
    __shared__ __attribute__((aligned(128))) __bf16 alds[2][B_ * BK];   // 2 x 16KB
    __shared__ __attribute__((aligned(128))) float  wlds[2][BK * PT];   // 2 x 8KB
    __shared__ __attribute__((aligned(128))) float  mlds[2][BK * PT];   // 2 x 8KB

    const int tid  = threadIdx.x;
    const int lane = tid & 63;
    const int wv   = tid >> 6;           // wave: bit0 = row-half, bit1 = p-slab
    const int ln   = lane & 31;
    const int hi   = lane >> 5;          // k-octet half (0..1)

    const int bid = blockIdx.x;          // 512 blocks
    const int pt  = bid & 7;             // p-tile -> XCD (mask slab + xb L2-hot)
    const int e   = bid >> 3;            // expert 0..63
    const int p0  = pt * PT;
    const int pl  = (wv >> 1) * 32 + ln; // p local 0..63 (B-frag col / epilogue)
    const int mrow0 = (wv & 1) * 128;

    const float* wbase = weight + (size_t)e * G_ * P_;

    floatx16 acc[4];
    #pragma unroll
    for (int i = 0; i < 4; ++i) acc[i] = (floatx16)0.f;

    // ---- stage tiles for K-step starting at kb into LDS buffer b2 ----
    auto stage = [&](int kb, int b2) {
        // A: 4 gll16/wave, 16 rows each
        #pragma unroll
        for (int i = 0; i < 4; ++i) {
            const int r0  = wv * 64 + i * 16;
            const int row = r0 + (lane >> 2);
            const int c   = (lane & 3) ^ ((row >> 1) & 3);
            if (USE_WS) {
                gll16(xb + (size_t)row * K2 + kb + c * 8, (void*)&alds[b2][r0 * BK]);
            } else {
                const int k0 = kb + c * 8;
                bf16x8 v;
                #pragma unroll
                for (int j = 0; j < 8; ++j)
                    v[j] = (k0 + j < G_) ? (__bf16)x[(size_t)row * G_ + k0 + j] : (__bf16)0.f;
                *(bf16x8*)&alds[b2][row * BK + (((lane & 3)) * 8)] = v;
            }
        }
        // W,M: 2 gll16/wave each, 4 g-rows per instr; clamp source row (tail)
        #pragma unroll
        for (int i = 0; i < 2; ++i) {
            const int gl = wv * 8 + i * 4 + (lane >> 4);
            int gg = kb + gl; if (gg > G_ - 1) gg = G_ - 1;   // in-bounds; A k-tail==0
            const size_t off = (size_t)gg * P_ + p0 + (lane & 15) * 4;
            gll16(wbase + off, (void*)&wlds[b2][(wv * 8 + i * 4) * PT]);
            gll16(mask  + off, (void*)&mlds[b2][(wv * 8 + i * 4) * PT]);
        }
    };

    // ---- prologue ----
    stage(0, 0);
    __syncthreads();

    // ---- main loop: all loads have one full step of latency cover ----
    for (int s = 0; s < NS; ++s) {
        const int buf = s & 1;
        if (s + 1 < NS) stage((s + 1) * BK, buf ^ 1);

        // build B frags from W/M LDS (b32 gather + mul + cvt)
        bf16x8 bfrag[2];
        #pragma unroll
        for (int kk = 0; kk < 2; ++kk)
            #pragma unroll
            for (int j = 0; j < 8; ++j) {
                const int g = kk * 16 + hi * 8 + j;
                bfrag[kk][j] = (__bf16)(wlds[buf][g * PT + pl] * mlds[buf][g * PT + pl]);
            }

        // 8 ds_read_b128 + 8 MFMA(32x32x16)
        #pragma unroll
        for (int kk = 0; kk < 2; ++kk) {
            #pragma unroll
            for (int mi = 0; mi < 4; ++mi) {
                const int row = mrow0 + mi * 32 + ln;
                const int c   = (kk * 2 + hi) ^ ((row >> 1) & 3);
                bf16x8 a = *(const bf16x8*)&alds[buf][row * BK + c * 8];
                acc[mi] = __builtin_amdgcn_mfma_f32_32x32x16_bf16(a, bfrag[kk], acc[mi], 0, 0, 0);
            }
        }

        __syncthreads();   // drains stage(s+1) glls; protects buffer swap
    }

    // ---- epilogue: D col n=p=lane&31, row m=(r&3)+8*(r>>2)+4*hi ----
    const float bv = bias[e * P_ + p0 + pl];
    #pragma unroll
    for (int mi = 0; mi < 4; ++mi) {
        #pragma unroll
        for (int r = 0; r < 16; ++r) {
            const int b = mrow0 + mi * 32 + (r & 3) + 8 * (r >> 2) + 4 * hi;
            __builtin_nontemporal_store(acc[mi][r] + bv,
                &out[(size_t)b * (E_ * P_) + (size_t)e * P_ + p0 + pl]);
        }
    }
}

extern "C" void kernel_launch(void* const* d_in, const int* in_sizes, int n_in,
                              void* d_out, int out_size, void* d_ws, size_t ws_size,
                              hipStream_t stream) {
    const float* x      = (const float*)d_in[0];
    const float* weight = (const float*)d_in[1];
    const float* bias   = (const float*)d_in[2];
    const float* mask   = (const float*)d_in[3];
    float* out = (float*)d_out;

    const size_t xb_bytes = (size_t)B_ * K2 * sizeof(__bf16);
    if (ws_size >= xb_bytes) {
        __bf16* xb = (__bf16*)d_ws;
        dim3 g1(K2 / 256, B_);
        cvt_x_kernel<<<g1, dim3(256), 0, stream>>>(x, xb);
        masked_gemm_kernel<true><<<dim3(512), dim3(256), 0, stream>>>(x, xb, weight, bias, mask, out);
    } else {
        masked_gemm_kernel<false><<<dim3(512), dim3(256), 0, stream>>>(x, nullptr, weight, bias, mask, out);
    }
}